// Round 4
// baseline (241.501 us; speedup 1.0000x reference)
//
#include <hip/hip_runtime.h>
#include <math.h>

#define NUM_TREES 4096
#define TOTAL_NODES 1048576
#define DCOL 256
#define DPW 64            // float4 elements per row (D=256 / 4)
#define CHUNK 256         // max rows per phase-1 wave
#define NC_MAX 8192       // sum ceil(s/CHUNK) <= 4096 + 4096 = 8192

// monotone float->uint encoding: unsigned max == float max
static __device__ __forceinline__ unsigned enc(float f) {
    unsigned b = __float_as_uint(f);
    return (b & 0x80000000u) ? ~b : (b | 0x80000000u);
}
static __device__ __forceinline__ float dec(unsigned u) {
    return (u & 0x80000000u) ? __uint_as_float(u ^ 0x80000000u)
                             : __uint_as_float(~u);
}
#define ENC_NEG_INF 0x007FFFFFu   // enc(-inf)

static __device__ __forceinline__ float4 f4max(float4 a, float4 b) {
    float4 r;
    r.x = fmaxf(a.x, b.x);
    r.y = fmaxf(a.y, b.y);
    r.z = fmaxf(a.z, b.z);
    r.w = fmaxf(a.w, b.w);
    return r;
}

// ---------------- Kernel 1: prefix sums of sizes and chunk counts ----------------
// tree_sizes dtype is int32 in practice (JAX x64 disabled downcasts jnp.int64),
// but auto-detect: if the int32 interpretation doesn't sum to TOTAL_NODES,
// re-read as int64. The int64 read only happens when the buffer really is 32KB.
__global__ void TreeAgg_prep(const void* __restrict__ sizes_raw,
                             int* __restrict__ row_off,
                             int* __restrict__ chunk_off) {
    __shared__ int s_row[256];
    __shared__ int s_chk[256];
    __shared__ int s_is64;
    const int t = threadIdx.x;          // 0..255, each owns 16 trees
    const int base = t * 16;
    const int* s32 = (const int*)sizes_raw;

    int ls[16];
    int rsum = 0;
    #pragma unroll
    for (int i = 0; i < 16; ++i) {
        ls[i] = s32[base + i];
        rsum += ls[i];
    }
    s_row[t] = rsum;
    __syncthreads();
    if (t == 0) {
        long long tot = 0;
        for (int i = 0; i < 256; ++i) tot += (long long)s_row[i];
        s_is64 = (tot != (long long)TOTAL_NODES) ? 1 : 0;
    }
    __syncthreads();
    if (s_is64) {
        const long long* s64 = (const long long*)sizes_raw;
        #pragma unroll
        for (int i = 0; i < 16; ++i) ls[i] = (int)s64[base + i];
    }

    int rs = 0, cs = 0;
    #pragma unroll
    for (int i = 0; i < 16; ++i) {
        rs += ls[i];
        cs += (ls[i] + CHUNK - 1) / CHUNK;
    }
    s_row[t] = rs;
    s_chk[t] = cs;
    __syncthreads();
    if (t == 0) {
        int ra = 0, ca = 0;
        for (int i = 0; i < 256; ++i) {
            int r = s_row[i], c = s_chk[i];
            s_row[i] = ra; s_chk[i] = ca;
            ra += r; ca += c;
        }
        row_off[NUM_TREES] = ra;      // == TOTAL_NODES
        chunk_off[NUM_TREES] = ca;    // == NC
    }
    __syncthreads();
    int ro = s_row[t], co = s_chk[t];
    #pragma unroll
    for (int i = 0; i < 16; ++i) {
        row_off[base + i] = ro;
        chunk_off[base + i] = co;
        ro += ls[i];
        co += (ls[i] + CHUNK - 1) / CHUNK;
    }
}

// ---------------- Kernel 2: init d_out to enc(-inf) ----------------
__global__ void TreeAgg_init(unsigned* __restrict__ out_u) {
    const int i = blockIdx.x * blockDim.x + threadIdx.x;   // 262144 uint4s
    uint4 v = make_uint4(ENC_NEG_INF, ENC_NEG_INF, ENC_NEG_INF, ENC_NEG_INF);
    ((uint4*)out_u)[i] = v;
}

// ---------------- Kernel 3: per-chunk max, atomic-encoded into d_out ----------------
__global__ void TreeAgg_partial(const float* __restrict__ emb,
                                const int* __restrict__ row_off,
                                const int* __restrict__ chunk_off,
                                unsigned* __restrict__ out_u) {
    const int wid  = (blockIdx.x * blockDim.x + threadIdx.x) >> 6;
    const int lane = threadIdx.x & 63;
    const int NC = chunk_off[NUM_TREES];
    if (wid >= NC) return;

    // binary search: largest t with chunk_off[t] <= wid  (wave-uniform)
    int lo = 0, hi = NUM_TREES;
    while (hi - lo > 1) {
        int mid = (lo + hi) >> 1;
        if (chunk_off[mid] <= wid) lo = mid; else hi = mid;
    }
    const int t  = lo;
    const int k  = wid - chunk_off[t];
    // fault-insurance clamps (wave-uniform scalar ops, ~free)
    int r0 = row_off[t] + k * CHUNK;
    int r1 = min(r0 + CHUNK, row_off[t + 1]);
    r1 = min(r1, TOTAL_NODES);
    r0 = max(0, min(r0, r1));
    if (r0 >= r1) return;

    const float4* __restrict__ src = (const float4*)emb;  // row r = float4 idx r*64
    const float NEG = -INFINITY;
    float4 acc = make_float4(NEG, NEG, NEG, NEG);

    long idx = (long)r0 * DPW + lane;
    int r = r0;
    for (; r + 4 <= r1; r += 4, idx += 4 * DPW) {
        float4 a = src[idx];
        float4 b = src[idx + DPW];
        float4 c = src[idx + 2 * DPW];
        float4 d = src[idx + 3 * DPW];
        acc = f4max(acc, f4max(f4max(a, b), f4max(c, d)));
    }
    for (; r < r1; ++r, idx += DPW) {
        acc = f4max(acc, src[idx]);
    }

    unsigned* dst = out_u + (long)t * DCOL + lane * 4;
    atomicMax(dst + 0, enc(acc.x));
    atomicMax(dst + 1, enc(acc.y));
    atomicMax(dst + 2, enc(acc.z));
    atomicMax(dst + 3, enc(acc.w));
}

// ---------------- Kernel 4: decode d_out in place ----------------
__global__ void TreeAgg_decode(unsigned* __restrict__ out_u) {
    const int i = blockIdx.x * blockDim.x + threadIdx.x;   // 262144 uint4s
    uint4 v = ((uint4*)out_u)[i];
    float4 f;
    f.x = dec(v.x); f.y = dec(v.y); f.z = dec(v.z); f.w = dec(v.w);
    ((float4*)out_u)[i] = f;
}

extern "C" void kernel_launch(void* const* d_in, const int* in_sizes, int n_in,
                              void* d_out, int out_size, void* d_ws, size_t ws_size,
                              hipStream_t stream) {
    const float* emb   = (const float*)d_in[0];
    const void*  sizes = d_in[1];                 // int32 or int64, auto-detected
    unsigned*    out_u = (unsigned*)d_out;

    // ws layout (no aliasing): row_off[4097] ints @0 (16388B),
    // chunk_off[4097] ints @20480. Total ~37KB.
    char* ws = (char*)d_ws;
    int* row_off   = (int*)(ws);
    int* chunk_off = (int*)(ws + 20480);

    TreeAgg_prep<<<1, 256, 0, stream>>>(sizes, row_off, chunk_off);

    // init d_out: 4096*256 uints = 262,144 uint4 -> 1024 blocks
    TreeAgg_init<<<1024, 256, 0, stream>>>(out_u);

    // main pass: NC_MAX waves (excess waves exit). 4 waves/block.
    const int p1_blocks = (NC_MAX * 64) / 256;   // 2048
    TreeAgg_partial<<<p1_blocks, 256, 0, stream>>>(emb, row_off, chunk_off, out_u);

    // decode in place
    TreeAgg_decode<<<1024, 256, 0, stream>>>(out_u);
}

// Round 5
// 238.687 us; speedup vs baseline: 1.0118x; 1.0118x over previous
//
#include <hip/hip_runtime.h>
#include <math.h>

#define NUM_TREES 4096
#define TOTAL_NODES 1048576
#define DCOL 256
#define DPW 64             // float4 elements per row (D=256 / 4)
#define SLICE 128          // rows per wave: 8192 waves * 128 rows = TOTAL_NODES
#define NWAVES 8192

static __device__ __forceinline__ float4 f4max(float4 a, float4 b) {
    float4 r;
    r.x = fmaxf(a.x, b.x);
    r.y = fmaxf(a.y, b.y);
    r.z = fmaxf(a.z, b.z);
    r.w = fmaxf(a.w, b.w);
    return r;
}

// float atomic max via CAS loop (safe, no HW-fmax dependency; avg <3 ops/address)
static __device__ __forceinline__ void atomicFmax(float* addr, float val) {
    unsigned* u = (unsigned*)addr;
    unsigned old = *u;                        // possibly stale; CAS self-corrects
    while (__uint_as_float(old) < val) {
        unsigned assumed = old;
        old = atomicCAS(u, assumed, __float_as_uint(val));
        if (old == assumed) break;
    }
}

// ---------------- Kernel 1 (fused): block 0 = row-offset prefix sum; all = init out to -inf ----
// tree_sizes dtype auto-detect (int32 in practice; int64 if x64 enabled) — proven in R4.
__global__ void TreeAgg_prep_init(const void* __restrict__ sizes_raw,
                                  int* __restrict__ row_off,
                                  float* __restrict__ out) {
    if (blockIdx.x == 0) {
        __shared__ int s_row[256];
        __shared__ int s_is64;
        const int t = threadIdx.x;            // each owns 16 trees
        const int base = t * 16;
        const int* s32 = (const int*)sizes_raw;

        int ls[16];
        int rsum = 0;
        #pragma unroll
        for (int i = 0; i < 16; ++i) { ls[i] = s32[base + i]; rsum += ls[i]; }
        s_row[t] = rsum;
        __syncthreads();
        if (t == 0) {
            long long tot = 0;
            for (int i = 0; i < 256; ++i) tot += (long long)s_row[i];
            s_is64 = (tot != (long long)TOTAL_NODES) ? 1 : 0;
        }
        __syncthreads();
        if (s_is64) {
            const long long* s64 = (const long long*)sizes_raw;
            #pragma unroll
            for (int i = 0; i < 16; ++i) ls[i] = (int)s64[base + i];
            int rs = 0;
            #pragma unroll
            for (int i = 0; i < 16; ++i) rs += ls[i];
            s_row[t] = rs;
            __syncthreads();
        }
        if (t == 0) {
            int ra = 0;
            for (int i = 0; i < 256; ++i) { int r = s_row[i]; s_row[i] = ra; ra += r; }
            row_off[NUM_TREES] = ra;          // == TOTAL_NODES
        }
        __syncthreads();
        int ro = s_row[t];
        #pragma unroll
        for (int i = 0; i < 16; ++i) { row_off[base + i] = ro; ro += ls[i]; }
    } else {
        // blocks 1..1024: init 262144 float4 of d_out to -inf
        const int i = (blockIdx.x - 1) * blockDim.x + threadIdx.x;
        const float NEG = -INFINITY;
        ((float4*)out)[i] = make_float4(NEG, NEG, NEG, NEG);
    }
}

// ---------------- Kernel 2: balanced streaming max ----------------
// Wave s owns rows [s*128, s*128+128): identical work per wave, split at tree
// boundaries, committed via float CAS-max. All 8192 waves co-resident (<=64 VGPR).
__global__ __launch_bounds__(256, 8)
void TreeAgg_main(const float* __restrict__ emb,
                  const int* __restrict__ row_off,
                  float* __restrict__ out) {
    const int wid  = (blockIdx.x * blockDim.x + threadIdx.x) >> 6;   // 0..8191
    const int lane = threadIdx.x & 63;

    int a = wid * SLICE;
    const int bend = a + SLICE;

    // binary search: largest t with row_off[t] <= a (wave-uniform)
    int lo = 0, hi = NUM_TREES;
    while (hi - lo > 1) {
        int mid = (lo + hi) >> 1;
        if (row_off[mid] <= a) lo = mid; else hi = mid;
    }
    int t = lo;

    const float4* __restrict__ src = (const float4*)emb;  // row r = float4 idx r*64
    const float NEG = -INFINITY;
    long idx = (long)a * DPW + lane;

    while (a < bend) {
        int b = min(bend, row_off[t + 1]);
        if (b <= a) break;                    // insurance vs corrupt offsets
        float4 acc = make_float4(NEG, NEG, NEG, NEG);
        int r = a;
        for (; r + 4 <= b; r += 4, idx += 4 * DPW) {
            float4 x = src[idx];
            float4 y = src[idx + DPW];
            float4 z = src[idx + 2 * DPW];
            float4 w = src[idx + 3 * DPW];
            acc = f4max(acc, f4max(f4max(x, y), f4max(z, w)));
        }
        for (; r < b; ++r, idx += DPW) {
            acc = f4max(acc, src[idx]);
        }
        float* dst = out + (long)t * DCOL + lane * 4;
        atomicFmax(dst + 0, acc.x);
        atomicFmax(dst + 1, acc.y);
        atomicFmax(dst + 2, acc.z);
        atomicFmax(dst + 3, acc.w);
        a = b;
        ++t;
    }
}

extern "C" void kernel_launch(void* const* d_in, const int* in_sizes, int n_in,
                              void* d_out, int out_size, void* d_ws, size_t ws_size,
                              hipStream_t stream) {
    const float* emb   = (const float*)d_in[0];
    const void*  sizes = d_in[1];                 // int32 or int64, auto-detected
    float*       out   = (float*)d_out;

    int* row_off = (int*)d_ws;                    // 4097 ints (~16.4 KB)

    // fused prep + init: block 0 prep, blocks 1..1024 init (1024*256 = 262144 float4)
    TreeAgg_prep_init<<<1025, 256, 0, stream>>>(sizes, row_off, out);

    // main: 8192 waves, 4 waves/block -> 2048 blocks
    TreeAgg_main<<<NWAVES * 64 / 256, 256, 0, stream>>>(emb, row_off, out);
}